// Round 5
// baseline (463.874 us; speedup 1.0000x reference)
//
#include <hip/hip_runtime.h>
#include <stdint.h>

// Problem constants
#define B_    8
#define CIN   1024
#define H_    64
#define W_    48
#define OC    512
#define HW    3072          // H*W
#define NPOS  24576         // B*H*W
#define K9    9216          // 9*CIN
#define HP    66            // H+2
#define WP    50            // W+2

typedef __attribute__((ext_vector_type(8))) __bf16 bf16x8;
typedef __attribute__((ext_vector_type(4))) float  float4_t;
typedef __attribute__((ext_vector_type(4))) unsigned short ushort4_t;
typedef __attribute__((ext_vector_type(8))) int int8v;
typedef __attribute__((ext_vector_type(4))) int int4v;

__device__ __forceinline__ unsigned short f2bf(float x) {
  union { float f; unsigned u; } v; v.f = x;
  unsigned r = v.u + 0x7FFFu + ((v.u >> 16) & 1u);
  return (unsigned short)(r >> 16);
}

// pack 4 floats -> 4 fp8 e4m3 bytes (RNE, saturating)
__device__ __forceinline__ unsigned int pack4_fp8(float a, float b, float c, float d) {
  int w = __builtin_amdgcn_cvt_pk_fp8_f32(a, b, 0, false);   // bytes 0,1
  w = __builtin_amdgcn_cvt_pk_fp8_f32(c, d, w, true);        // bytes 2,3
  return (unsigned int)w;
}

__device__ __forceinline__ void async16(const void* g, void* l) {
  __builtin_amdgcn_global_load_lds(
      (const __attribute__((address_space(1))) unsigned int*)g,
      (__attribute__((address_space(3))) unsigned int*)l, 16, 0, 0);
}

__device__ __forceinline__ float wave_sum(float v) {
  for (int o = 32; o > 0; o >>= 1) v += __shfl_down(v, o, 64);
  return v;
}

// ================= fused prep (R3 layout — R4 variant regressed) =========================
// grid = 4096 (prep_x) + 512 (prep_w) + 32 (prep_wh) + 528 (borders) = 5168, 256 threads
__global__ void prep_fused(const float* __restrict__ x, const float* __restrict__ Wc,
                           const float* __restrict__ Wcls, const float* __restrict__ Wbb,
                           unsigned char* __restrict__ xt, unsigned char* __restrict__ Wa,
                           unsigned short* __restrict__ Wh, float* __restrict__ accbuf) {
  __shared__ float smem[9216];   // 36 KB shared across branches
  int bid = blockIdx.x, t = threadIdx.x;
  if (bid < 4096) {
    // ---- prep_x: pad+transpose NCHW fp32 -> NHWC fp8 (x16), one (b,h,128c) slice ----
    int cx = bid & 7, h = (bid >> 3) & 63, b = bid >> 9;
    float* tile = smem;   // [128][49]
    const float* src = x + ((long)(b * CIN + cx * 128) * H_ + h) * W_;
    for (int it = 0; it < 6; ++it) {
      int e = it * 256 + t;
      int cl = e / 12, w4 = e % 12;
      float4_t v = *(const float4_t*)&src[(long)cl * HW + w4 * 4];
      int base = cl * 49 + w4 * 4;
      tile[base] = v.x; tile[base + 1] = v.y; tile[base + 2] = v.z; tile[base + 3] = v.w;
    }
    __syncthreads();
    unsigned char* dst = xt + ((long)(b * HP + h + 1) * WP + 1) * CIN + cx * 128;
    for (int it = 0; it < 6; ++it) {
      int e = it * 256 + t;
      int w = e >> 5, g = e & 31;
      float v0 = tile[(g * 4 + 0) * 49 + w] * 16.f;
      float v1 = tile[(g * 4 + 1) * 49 + w] * 16.f;
      float v2 = tile[(g * 4 + 2) * 49 + w] * 16.f;
      float v3 = tile[(g * 4 + 3) * 49 + w] * 16.f;
      *(unsigned int*)&dst[(long)w * CIN + g * 4] = pack4_fp8(v0, v1, v2, v3);
    }
  } else if (bid < 4608) {
    // ---- prep_w: W_conv [512,1024,3,3] -> Wa [512,9216] fp8 (x512), k=(off*1024+c) ----
    int o = bid - 4096;
    float* lw = smem;
    const float* src = Wc + (long)o * K9;
    for (int i = 0; i < 9; ++i)
      *(float4_t*)&lw[i * 1024 + t * 4] = *(const float4_t*)&src[i * 1024 + t * 4];
    __syncthreads();
    unsigned char* dst = Wa + (long)o * K9;
    int c = t * 4;
    for (int off = 0; off < 9; ++off) {
      float v0 = lw[(c + 0) * 9 + off] * 512.f;
      float v1 = lw[(c + 1) * 9 + off] * 512.f;
      float v2 = lw[(c + 2) * 9 + off] * 512.f;
      float v3 = lw[(c + 3) * 9 + off] * 512.f;
      *(unsigned int*)&dst[off * 1024 + c] = pack4_fp8(v0, v1, v2, v3);
    }
  } else if (bid < 4640) {
    // ---- prep_wh: head weights -> Wh [64,512] bf16 (rows 54..63 zero) ----
    int e = (bid - 4608) * 1024 + t * 4;
    int m = e >> 9, c = e & 511;
    float v0 = 0.f, v1 = 0.f, v2 = 0.f, v3 = 0.f;
    if (m < 18) {
      const float* s = Wcls + m * 512 + c;
      v0 = s[0]; v1 = s[1]; v2 = s[2]; v3 = s[3];
    } else if (m < 54) {
      const float* s = Wbb + (m - 18) * 512 + c;
      v0 = s[0]; v1 = s[1]; v2 = s[2]; v3 = s[3];
    }
    ushort4_t pk; pk.x = f2bf(v0); pk.y = f2bf(v1); pk.z = f2bf(v2); pk.w = f2bf(v3);
    *(ushort4_t*)&Wh[e] = pk;
    if (bid == 4608 && t < 4) accbuf[t] = 0.f;   // sums[3] + ticket
  } else {
    // ---- borders: zero-pad halo of xt ----
    int bid2 = bid - 4640;
    int b = bid2 / 66, h = bid2 % 66;
    unsigned char* base = xt + (long)(b * 66 + h) * 50 * 1024;
    int4v z = {};
    if (h == 0 || h == 65) {
      for (int i = t; i < 3200; i += 256) *(int4v*)(base + (long)i * 16) = z;
    } else if (t < 128) {
      int which = t >> 6, off = t & 63;
      *(int4v*)(base + (long)which * 49 * 1024 + (long)off * 16) = z;
    }
  }
}

// ---------------- main conv GEMM (MX-fp8): M=512, N=24576, K=9216 ------------------------
// 128x128 tile, K-step 128 (fp8). grid (192, 4), 256 threads.
// Single-barrier double-buffered K-loop: stage kt+1 after the barrier, compute kt.
#define BKF 128
__global__ __launch_bounds__(256, 2)
void conv_gemm(const unsigned char* __restrict__ Wa, const unsigned char* __restrict__ xt,
               const float* __restrict__ bias, unsigned short* __restrict__ conv1) {
  __shared__ unsigned char As[2][128 * BKF];   // 2 x 16 KB
  __shared__ unsigned char Bs[2][128 * BKF];   // 2 x 16 KB
  int t = threadIdx.x;
  int lane = t & 63, wv = t >> 6;
  int m0 = blockIdx.y * 128;
  int n0 = blockIdx.x * 128;
  const unsigned char* aSrc[4];
  const unsigned char* bSrc[4];
  for (int s = 0; s < 4; ++s) {
    int c = s * 256 + t;
    int r = c >> 3;
    int q = (c & 7) ^ (r & 7);
    aSrc[s] = Wa + (long)(m0 + r) * K9 + q * 16;
    int n = n0 + r; int b = n / HW; int rem = n % HW; int h = rem / W_; int w = rem % W_;
    bSrc[s] = xt + ((long)(b * HP + h) * WP + w) * CIN + q * 16;
  }
  float4_t acc[4][4] = {};
  int wm = wv >> 1, wn = wv & 1;
  int quad = lane >> 4, col = lane & 15;

  auto stage = [&](int kt, int pb) {
    int off = kt >> 3;                       // which of the 9 (dy,dx) taps
    int dy = off / 3, dx = off % 3;
    long boff = (long)(dy * WP + dx) * CIN + (kt & 7) * 128;
    long aoff = (long)kt * 128;
    for (int s = 0; s < 4; ++s)
      async16(aSrc[s] + aoff, &As[pb][s * 4096 + wv * 1024]);
    for (int s = 0; s < 4; ++s)
      async16(bSrc[s] + boff, &Bs[pb][s * 4096 + wv * 1024]);
  };

  stage(0, 0);
  for (int kt = 0; kt < 72; ++kt) {
    int pb = kt & 1;
    __syncthreads();                 // drains staging of tile kt; frees buffer pb^1
    if (kt < 71) stage(kt + 1, pb ^ 1);
    int8v af[4], bfr[4];
    for (int i = 0; i < 4; ++i) {
      int r = wm * 64 + i * 16 + col;
      int rb = r * 128, x7 = r & 7;
      int4v lo = *(const int4v*)&As[pb][rb + (((quad * 2 + 0) ^ x7) << 4)];
      int4v hi = *(const int4v*)&As[pb][rb + (((quad * 2 + 1) ^ x7) << 4)];
      af[i] = (int8v){lo.x, lo.y, lo.z, lo.w, hi.x, hi.y, hi.z, hi.w};
    }
    for (int j = 0; j < 4; ++j) {
      int r = wn * 64 + j * 16 + col;
      int rb = r * 128, x7 = r & 7;
      int4v lo = *(const int4v*)&Bs[pb][rb + (((quad * 2 + 0) ^ x7) << 4)];
      int4v hi = *(const int4v*)&Bs[pb][rb + (((quad * 2 + 1) ^ x7) << 4)];
      bfr[j] = (int8v){lo.x, lo.y, lo.z, lo.w, hi.x, hi.y, hi.z, hi.w};
    }
    for (int i = 0; i < 4; ++i)
      for (int j = 0; j < 4; ++j)
        // A=W scaled by 2^9 -> e8m0 118 (2^-9); B=x scaled by 2^4 -> e8m0 123 (2^-4)
        acc[i][j] = __builtin_amdgcn_mfma_scale_f32_16x16x128_f8f6f4(
            af[i], bfr[j], acc[i][j], 0, 0, 0, 0x76767676, 0, 0x7B7B7B7B);
  }
  // epilogue: bias + relu, store bf16 conv1[n*512 + m], 8B packed along m
  for (int i = 0; i < 4; ++i) {
    int mb = m0 + wm * 64 + i * 16 + quad * 4;
    float b0 = bias[mb + 0], b1 = bias[mb + 1], b2 = bias[mb + 2], b3 = bias[mb + 3];
    for (int j = 0; j < 4; ++j) {
      int n = n0 + wn * 64 + j * 16 + col;
      ushort4_t pk;
      pk.x = f2bf(fmaxf(acc[i][j].x + b0, 0.f));
      pk.y = f2bf(fmaxf(acc[i][j].y + b1, 0.f));
      pk.z = f2bf(fmaxf(acc[i][j].z + b2, 0.f));
      pk.w = f2bf(fmaxf(acc[i][j].w + b3, 0.f));
      *(ushort4_t*)&conv1[(long)n * 512 + mb] = pk;
    }
  }
}

// ---------------- head GEMM: [64 x 512] @ conv1^T -> cls_score (ws) + bbox_pred (d_out) --
// M=64 (54 used), N=24576, K=512. Tile 64(N) x BK=128. grid 384, 256 threads.
__global__ __launch_bounds__(256, 2)
void head_gemm(const unsigned short* __restrict__ Wh, const unsigned short* __restrict__ conv1,
               const float* __restrict__ b_cls, const float* __restrict__ b_bbox,
               float* __restrict__ cls_ws, float* __restrict__ out_bbox) {
  __shared__ unsigned short As[64 * 128];   // 16 KB
  __shared__ unsigned short Bs[64 * 128];   // 16 KB
  int t = threadIdx.x;
  int lane = t & 63, wv = t >> 6;
  int n0 = blockIdx.x * 64;
  int quad = lane >> 4, col = lane & 15;
  const unsigned short* aS[4];
  const unsigned short* bS[4];
  for (int p = 0; p < 4; ++p) {
    int c = p * 256 + t;
    int r = c >> 4;
    int q = (c & 15) ^ (r & 15);
    aS[p] = Wh + (long)r * 512 + q * 8;
    bS[p] = conv1 + (long)(n0 + r) * 512 + q * 8;
  }
  float4_t acc[4] = {};
  for (int kt = 0; kt < 4; ++kt) {
    long koff = (long)kt * 128;
    __syncthreads();
    for (int p = 0; p < 4; ++p) async16(aS[p] + koff, &As[p * 2048 + wv * 512]);
    for (int p = 0; p < 4; ++p) async16(bS[p] + koff, &Bs[p * 2048 + wv * 512]);
    __syncthreads();
    for (int ks = 0; ks < 4; ++ks) {
      int rn = wv * 16 + col;
      bf16x8 bfr = *(const bf16x8*)&Bs[rn * 128 + (((ks * 4 + quad) ^ (rn & 15)) << 3)];
      for (int i = 0; i < 4; ++i) {
        int r = i * 16 + col;
        bf16x8 af = *(const bf16x8*)&As[r * 128 + (((ks * 4 + quad) ^ (r & 15)) << 3)];
        acc[i] = __builtin_amdgcn_mfma_f32_16x16x32_bf16(af, bfr, acc[i], 0, 0, 0);
      }
    }
  }
  int n = n0 + wv * 16 + col;
  int b = n / HW; int rem = n % HW;   // rem = h*48 + w
  for (int i = 0; i < 4; ++i) {
    for (int r = 0; r < 4; ++r) {
      int m = i * 16 + quad * 4 + r;
      float v = acc[i][r];
      if (m < 18) {
        cls_ws[(long)(b * 18 + m) * HW + rem] = v + b_cls[m];
      } else if (m < 54) {
        out_bbox[(long)(b * 36 + (m - 18)) * HW + rem] = v + b_bbox[m - 18];
      }
    }
  }
}

// ---------------- fused losses + finalize (device-scope ticket) --------------------------
// blocks 0..863: softmax+NLL; 864..2591: smooth-L1 box; last ticket writes out scalars
__global__ void loss_fused(const float* __restrict__ cls, const int* __restrict__ label,
                           float* __restrict__ prob,
                           const float* __restrict__ pred, const float* __restrict__ tgt,
                           const float* __restrict__ iw, const float* __restrict__ ow,
                           float* __restrict__ acc, float* __restrict__ out_scalars) {
  int lane = threadIdx.x & 63, wv = threadIdx.x >> 6;
  __shared__ float red[8];
  if (blockIdx.x < 864) {
    int idx = blockIdx.x * 256 + threadIdx.x;
    int b = idx / 27648; int r = idx % 27648;
    int a = r / HW; int r2 = r % HW;
    long i0 = (long)(b * 18 + a) * HW + r2;
    long i1 = i0 + (long)9 * HW;
    float x0 = cls[i0], x1 = cls[i1];
    float mx = fmaxf(x0, x1);
    float e0 = __expf(x0 - mx), e1 = __expf(x1 - mx);
    float s = e0 + e1;
    prob[i0] = e0 / s;
    prob[i1] = e1 / s;
    int lb = label[idx];
    float nll = 0.f, val = 0.f;
    if (lb != -1) {
      val = 1.f;
      float xl = (lb > 0) ? x1 : x0;
      nll = -(xl - mx - __logf(s));
    }
    nll = wave_sum(nll);
    val = wave_sum(val);
    if (lane == 0) { red[wv] = nll; red[4 + wv] = val; }
    __syncthreads();
    if (threadIdx.x == 0) {
      atomicAdd(&acc[0], red[0] + red[1] + red[2] + red[3]);
      atomicAdd(&acc[1], red[4] + red[5] + red[6] + red[7]);
    }
  } else {
    int bid = blockIdx.x - 864;
    float s = 0.f;
    const long total = (long)B_ * 36 * HW;   // 884736
    for (long i = (long)bid * 256 + threadIdx.x; i < total; i += (long)1728 * 256) {
      float d = iw[i] * (pred[i] - tgt[i]);
      float ad = fabsf(d);
      float l = (ad < (1.f / 9.f)) ? d * d * 4.5f : ad - (1.f / 18.f);
      s += ow[i] * l;
    }
    s = wave_sum(s);
    if (lane == 0) red[wv] = s;
    __syncthreads();
    if (threadIdx.x == 0) atomicAdd(&acc[2], red[0] + red[1] + red[2] + red[3]);
  }
  if (threadIdx.x == 0) {
    __threadfence();
    float tk = atomicAdd(&acc[3], 1.f);
    if (tk == 2591.f) {
      float c0 = atomicAdd(&acc[0], 0.f);
      float c1 = atomicAdd(&acc[1], 0.f);
      float c2 = atomicAdd(&acc[2], 0.f);
      out_scalars[0] = c0 / fmaxf(c1, 1.f);
      out_scalars[1] = c2 / (float)B_;
    }
  }
}

extern "C" void kernel_launch(void* const* d_in, const int* in_sizes, int n_in,
                              void* d_out, int out_size, void* d_ws, size_t ws_size,
                              hipStream_t stream) {
  const float* base_feat = (const float*)d_in[0];
  const float* W_conv    = (const float*)d_in[1];
  const float* b_conv    = (const float*)d_in[2];
  const float* W_cls     = (const float*)d_in[3];
  const float* b_cls     = (const float*)d_in[4];
  const float* W_bbox    = (const float*)d_in[5];
  const float* b_bbox    = (const float*)d_in[6];
  const int*   rpn_label = (const int*)d_in[7];
  const float* bb_tgt    = (const float*)d_in[8];
  const float* bb_iw     = (const float*)d_in[9];
  const float* bb_ow     = (const float*)d_in[10];

  float* out = (float*)d_out;
  float* out_cls_prob = out;                         // 442368
  float* out_bbox     = out + 442368;                // 884736
  float* out_scalars  = out + 442368 + 884736;       // 2

  // workspace layout
  size_t off = 0;
  auto alloc = [&](size_t bytes) {
    void* p = (char*)d_ws + off;
    off = (off + bytes + 255) & ~(size_t)255;
    return p;
  };
  const size_t XT_BYTES = (size_t)B_ * HP * WP * CIN;              // 27,033,600 (fp8)
  unsigned char*  xt    = (unsigned char*)alloc(XT_BYTES);
  unsigned char*  Wa    = (unsigned char*)alloc((size_t)OC * K9);
  unsigned short* conv1 = (unsigned short*)alloc((size_t)NPOS * OC * 2);
  unsigned short* Wh    = (unsigned short*)alloc((size_t)64 * 512 * 2);
  float* cls_ws         = (float*)alloc((size_t)B_ * 18 * HW * 4);
  float* accbuf         = (float*)alloc(16);

  prep_fused<<<5168, 256, 0, stream>>>(base_feat, W_conv, W_cls, W_bbox, xt, Wa, Wh, accbuf);
  conv_gemm<<<dim3(192, 4), 256, 0, stream>>>(Wa, xt, b_conv, conv1);
  head_gemm<<<384, 256, 0, stream>>>(Wh, conv1, b_cls, b_bbox, cls_ws, out_bbox);
  loss_fused<<<2592, 256, 0, stream>>>(cls_ws, rpn_label, out_cls_prob,
                                       out_bbox, bb_tgt, bb_iw, bb_ow, accbuf, out_scalars);
}

// Round 6
// 394.313 us; speedup vs baseline: 1.1764x; 1.1764x over previous
//
#include <hip/hip_runtime.h>
#include <stdint.h>

// Problem constants
#define B_    8
#define CIN   1024
#define H_    64
#define W_    48
#define OC    512
#define HW    3072          // H*W
#define NPOS  24576         // B*H*W
#define K9    9216          // 9*CIN
#define HP    66            // H+2
#define WP    50            // W+2

typedef __attribute__((ext_vector_type(8))) __bf16 bf16x8;
typedef __attribute__((ext_vector_type(4))) float  float4_t;
typedef __attribute__((ext_vector_type(4))) unsigned short ushort4_t;
typedef __attribute__((ext_vector_type(8))) int int8v;
typedef __attribute__((ext_vector_type(4))) int int4v;

__device__ __forceinline__ unsigned short f2bf(float x) {
  union { float f; unsigned u; } v; v.f = x;
  unsigned r = v.u + 0x7FFFu + ((v.u >> 16) & 1u);
  return (unsigned short)(r >> 16);
}

// pack 4 floats -> 4 fp8 e4m3 bytes (RNE, saturating)
__device__ __forceinline__ unsigned int pack4_fp8(float a, float b, float c, float d) {
  int w = __builtin_amdgcn_cvt_pk_fp8_f32(a, b, 0, false);   // bytes 0,1
  w = __builtin_amdgcn_cvt_pk_fp8_f32(c, d, w, true);        // bytes 2,3
  return (unsigned int)w;
}

__device__ __forceinline__ void async16(const void* g, void* l) {
  __builtin_amdgcn_global_load_lds(
      (const __attribute__((address_space(1))) unsigned int*)g,
      (__attribute__((address_space(3))) unsigned int*)l, 16, 0, 0);
}

__device__ __forceinline__ float wave_sum(float v) {
  for (int o = 32; o > 0; o >>= 1) v += __shfl_down(v, o, 64);
  return v;
}

// ================= fused prep (R3 layout) ================================================
// [0,4096): prep_x  [4096,4608): prep_w  [4608,4640): prep_wh  [4640,5168): borders
// [5168,5552): zero head_acc
__global__ void prep_fused(const float* __restrict__ x, const float* __restrict__ Wc,
                           const float* __restrict__ Wcls, const float* __restrict__ Wbb,
                           unsigned char* __restrict__ xt, unsigned char* __restrict__ Wa,
                           unsigned short* __restrict__ Wh, float* __restrict__ accbuf,
                           float* __restrict__ head_acc) {
  __shared__ float smem[9216];   // 36 KB shared across branches
  int bid = blockIdx.x, t = threadIdx.x;
  if (bid < 4096) {
    // ---- prep_x: pad+transpose NCHW fp32 -> NHWC fp8 (x16), one (b,h,128c) slice ----
    int cx = bid & 7, h = (bid >> 3) & 63, b = bid >> 9;
    float* tile = smem;   // [128][49]
    const float* src = x + ((long)(b * CIN + cx * 128) * H_ + h) * W_;
    for (int it = 0; it < 6; ++it) {
      int e = it * 256 + t;
      int cl = e / 12, w4 = e % 12;
      float4_t v = *(const float4_t*)&src[(long)cl * HW + w4 * 4];
      int base = cl * 49 + w4 * 4;
      tile[base] = v.x; tile[base + 1] = v.y; tile[base + 2] = v.z; tile[base + 3] = v.w;
    }
    __syncthreads();
    unsigned char* dst = xt + ((long)(b * HP + h + 1) * WP + 1) * CIN + cx * 128;
    for (int it = 0; it < 6; ++it) {
      int e = it * 256 + t;
      int w = e >> 5, g = e & 31;
      float v0 = tile[(g * 4 + 0) * 49 + w] * 16.f;
      float v1 = tile[(g * 4 + 1) * 49 + w] * 16.f;
      float v2 = tile[(g * 4 + 2) * 49 + w] * 16.f;
      float v3 = tile[(g * 4 + 3) * 49 + w] * 16.f;
      *(unsigned int*)&dst[(long)w * CIN + g * 4] = pack4_fp8(v0, v1, v2, v3);
    }
  } else if (bid < 4608) {
    // ---- prep_w: W_conv [512,1024,3,3] -> Wa [512,9216] fp8 (x512), k=(off*1024+c) ----
    int o = bid - 4096;
    float* lw = smem;
    const float* src = Wc + (long)o * K9;
    for (int i = 0; i < 9; ++i)
      *(float4_t*)&lw[i * 1024 + t * 4] = *(const float4_t*)&src[i * 1024 + t * 4];
    __syncthreads();
    unsigned char* dst = Wa + (long)o * K9;
    int c = t * 4;
    for (int off = 0; off < 9; ++off) {
      float v0 = lw[(c + 0) * 9 + off] * 512.f;
      float v1 = lw[(c + 1) * 9 + off] * 512.f;
      float v2 = lw[(c + 2) * 9 + off] * 512.f;
      float v3 = lw[(c + 3) * 9 + off] * 512.f;
      *(unsigned int*)&dst[off * 1024 + c] = pack4_fp8(v0, v1, v2, v3);
    }
  } else if (bid < 4640) {
    // ---- prep_wh: head weights -> Wh [64,512] bf16 (rows 54..63 zero) ----
    int e = (bid - 4608) * 1024 + t * 4;
    int m = e >> 9, c = e & 511;
    float v0 = 0.f, v1 = 0.f, v2 = 0.f, v3 = 0.f;
    if (m < 18) {
      const float* s = Wcls + m * 512 + c;
      v0 = s[0]; v1 = s[1]; v2 = s[2]; v3 = s[3];
    } else if (m < 54) {
      const float* s = Wbb + (m - 18) * 512 + c;
      v0 = s[0]; v1 = s[1]; v2 = s[2]; v3 = s[3];
    }
    ushort4_t pk; pk.x = f2bf(v0); pk.y = f2bf(v1); pk.z = f2bf(v2); pk.w = f2bf(v3);
    *(ushort4_t*)&Wh[e] = pk;
    if (bid == 4608 && t < 4) accbuf[t] = 0.f;   // sums[3] + ticket
  } else if (bid < 5168) {
    // ---- borders: zero-pad halo of xt ----
    int bid2 = bid - 4640;
    int b = bid2 / 66, h = bid2 % 66;
    unsigned char* base = xt + (long)(b * 66 + h) * 50 * 1024;
    int4v z = {};
    if (h == 0 || h == 65) {
      for (int i = t; i < 3200; i += 256) *(int4v*)(base + (long)i * 16) = z;
    } else if (t < 128) {
      int which = t >> 6, off = t & 63;
      *(int4v*)(base + (long)which * 49 * 1024 + (long)off * 16) = z;
    }
  } else {
    // ---- zero head_acc: 64*24576 fp32 = 6.29 MB over 384 blocks ----
    long base = (long)(bid - 5168) * 4096 + t * 16;
    float4_t z = {};
    for (int i = 0; i < 4; ++i) *(float4_t*)&head_acc[base + i * 4] = z;
  }
}

// ---------------- main conv GEMM (MX-fp8) + fused head epilogue --------------------------
// M=512, N=24576, K=9216. 128x128 tile, K-step 128. grid (192, 4), 256 threads.
// After K-loop: relu -> bf16 P[n][m] in LDS (reusing As/Bs, xor-swizzled) -> head MFMA
// -> atomicAdd partials into head_acc[64][24576].
#define BKF 128
__global__ __launch_bounds__(256, 2)
void conv_gemm(const unsigned char* __restrict__ Wa, const unsigned char* __restrict__ xt,
               const float* __restrict__ bias, const unsigned short* __restrict__ Wh,
               float* __restrict__ head_acc) {
  __shared__ __align__(16) unsigned char sm[32768];
  unsigned char* As = sm;            // 16 KB
  unsigned char* Bs = sm + 16384;    // 16 KB
  unsigned short* P = (unsigned short*)sm;   // [128 n][128 m] bf16, chunk-swizzled
  int t = threadIdx.x;
  int lane = t & 63, wv = t >> 6;
  int m0 = blockIdx.y * 128;
  int n0 = blockIdx.x * 128;
  const unsigned char* aSrc[4];
  const unsigned char* bSrc[4];
  for (int s = 0; s < 4; ++s) {
    int c = s * 256 + t;
    int r = c >> 3;
    int q = (c & 7) ^ (r & 7);
    aSrc[s] = Wa + (long)(m0 + r) * K9 + q * 16;
    int n = n0 + r; int b = n / HW; int rem = n % HW; int h = rem / W_; int w = rem % W_;
    bSrc[s] = xt + ((long)(b * HP + h) * WP + w) * CIN + q * 16;
  }
  float4_t acc[4][4] = {};
  int wm = wv >> 1, wn = wv & 1;
  int quad = lane >> 4, col = lane & 15;
  for (int kt = 0; kt < 72; ++kt) {
    int off = kt >> 3;                       // which of the 9 (dy,dx) taps
    int dy = off / 3, dx = off % 3;
    long boff = (long)(dy * WP + dx) * CIN + (kt & 7) * 128;
    long aoff = (long)kt * 128;
    __syncthreads();
    for (int s = 0; s < 4; ++s)
      async16(aSrc[s] + aoff, &As[s * 4096 + wv * 1024]);
    for (int s = 0; s < 4; ++s)
      async16(bSrc[s] + boff, &Bs[s * 4096 + wv * 1024]);
    __syncthreads();
    int8v af[4], bfr[4];
    for (int i = 0; i < 4; ++i) {
      int r = wm * 64 + i * 16 + col;
      int rb = r * 128, x7 = r & 7;
      int4v lo = *(const int4v*)&As[rb + (((quad * 2 + 0) ^ x7) << 4)];
      int4v hi = *(const int4v*)&As[rb + (((quad * 2 + 1) ^ x7) << 4)];
      af[i] = (int8v){lo.x, lo.y, lo.z, lo.w, hi.x, hi.y, hi.z, hi.w};
    }
    for (int j = 0; j < 4; ++j) {
      int r = wn * 64 + j * 16 + col;
      int rb = r * 128, x7 = r & 7;
      int4v lo = *(const int4v*)&Bs[rb + (((quad * 2 + 0) ^ x7) << 4)];
      int4v hi = *(const int4v*)&Bs[rb + (((quad * 2 + 1) ^ x7) << 4)];
      bfr[j] = (int8v){lo.x, lo.y, lo.z, lo.w, hi.x, hi.y, hi.z, hi.w};
    }
    for (int i = 0; i < 4; ++i)
      for (int j = 0; j < 4; ++j)
        // A=W scaled by 2^9 -> e8m0 118 (2^-9); B=x scaled by 2^4 -> e8m0 123 (2^-4)
        acc[i][j] = __builtin_amdgcn_mfma_scale_f32_16x16x128_f8f6f4(
            af[i], bfr[j], acc[i][j], 0, 0, 0, 0x76767676, 0, 0x7B7B7B7B);
  }
  // ---- epilogue 1: bias + relu -> bf16 into swizzled P[n][m] ----
  // P byte addr: n*256 + ((chunk ^ (n&15))<<4) + (m&7)*2, chunk = m>>3 (16B = 8 bf16)
  __syncthreads();   // all waves done reading As/Bs
  for (int i = 0; i < 4; ++i) {
    int mb = m0 + wm * 64 + i * 16 + quad * 4;
    int ml = wm * 64 + i * 16 + quad * 4;      // local m of first of 4
    float b0 = bias[mb + 0], b1 = bias[mb + 1], b2 = bias[mb + 2], b3 = bias[mb + 3];
    int chunk = ml >> 3, sub = ml & 7;
    for (int j = 0; j < 4; ++j) {
      int nl = wn * 64 + j * 16 + col;
      ushort4_t pk;
      pk.x = f2bf(fmaxf(acc[i][j].x + b0, 0.f));
      pk.y = f2bf(fmaxf(acc[i][j].y + b1, 0.f));
      pk.z = f2bf(fmaxf(acc[i][j].z + b2, 0.f));
      pk.w = f2bf(fmaxf(acc[i][j].w + b3, 0.f));
      *(ushort4_t*)((unsigned char*)P + nl * 256 + (((chunk ^ (nl & 15)) << 4) + sub * 2)) = pk;
    }
  }
  __syncthreads();
  // ---- epilogue 2: head partial GEMM. D2[mh 64][n 128] over k=local m 128 ----
  // wave wv owns n-range [wv*32, wv*32+32)
  for (int mt = 0; mt < 4; ++mt) {
    for (int nt = 0; nt < 2; ++nt) {
      int nl = wv * 32 + nt * 16 + col;
      float4_t acc2 = {};
      for (int ks = 0; ks < 4; ++ks) {
        // A2 row = mh = mt*16+col, k = ks*32 + quad*8 ; global m = m0 + k
        bf16x8 af2 = *(const bf16x8*)&Wh[(mt * 16 + col) * 512 + m0 + ks * 32 + quad * 8];
        int ch = ks * 4 + quad;
        bf16x8 bf2 = *(const bf16x8*)((unsigned char*)P + nl * 256 + ((ch ^ (nl & 15)) << 4));
        acc2 = __builtin_amdgcn_mfma_f32_16x16x32_bf16(af2, bf2, acc2, 0, 0, 0);
      }
      int n = n0 + nl;
      for (int r = 0; r < 4; ++r) {
        int mh = mt * 16 + quad * 4 + r;
        if (mh < 54) atomicAdd(&head_acc[(long)mh * NPOS + n], acc2[r]);
      }
    }
  }
}

// ---------------- fused losses + outputs + finalize --------------------------------------
// blocks 0..863: softmax+NLL -> out_cls_prob; 864..2591: bbox_pred out + smooth-L1 box
__global__ void loss_fused(const float* __restrict__ head_acc, const int* __restrict__ label,
                           const float* __restrict__ b_cls, const float* __restrict__ b_bbox,
                           float* __restrict__ prob, float* __restrict__ out_bbox,
                           const float* __restrict__ tgt,
                           const float* __restrict__ iw, const float* __restrict__ ow,
                           float* __restrict__ acc, float* __restrict__ out_scalars) {
  int lane = threadIdx.x & 63, wv = threadIdx.x >> 6;
  __shared__ float red[8];
  if (blockIdx.x < 864) {
    int idx = blockIdx.x * 256 + threadIdx.x;
    int b = idx / 27648; int r = idx % 27648;
    int a = r / HW; int r2 = r % HW;
    long nn = (long)b * HW + r2;
    float x0 = head_acc[(long)a * NPOS + nn] + b_cls[a];
    float x1 = head_acc[(long)(a + 9) * NPOS + nn] + b_cls[a + 9];
    float mx = fmaxf(x0, x1);
    float e0 = __expf(x0 - mx), e1 = __expf(x1 - mx);
    float s = e0 + e1;
    long i0 = (long)(b * 18 + a) * HW + r2;
    prob[i0] = e0 / s;
    prob[i0 + (long)9 * HW] = e1 / s;
    int lb = label[idx];
    float nll = 0.f, val = 0.f;
    if (lb != -1) {
      val = 1.f;
      float xl = (lb > 0) ? x1 : x0;
      nll = -(xl - mx - __logf(s));
    }
    nll = wave_sum(nll);
    val = wave_sum(val);
    if (lane == 0) { red[wv] = nll; red[4 + wv] = val; }
    __syncthreads();
    if (threadIdx.x == 0) {
      atomicAdd(&acc[0], red[0] + red[1] + red[2] + red[3]);
      atomicAdd(&acc[1], red[4] + red[5] + red[6] + red[7]);
    }
  } else {
    int bid = blockIdx.x - 864;
    float s = 0.f;
    const long total = (long)B_ * 36 * HW;   // 884736
    for (long i = (long)bid * 256 + threadIdx.x; i < total; i += (long)1728 * 256) {
      int hw = (int)(i % HW);
      int c = (int)((i / HW) % 36);
      int b = (int)(i / (36 * HW));
      float pv = head_acc[(long)(18 + c) * NPOS + (long)b * HW + hw] + b_bbox[c];
      out_bbox[i] = pv;
      float d = iw[i] * (pv - tgt[i]);
      float ad = fabsf(d);
      float l = (ad < (1.f / 9.f)) ? d * d * 4.5f : ad - (1.f / 18.f);
      s += ow[i] * l;
    }
    s = wave_sum(s);
    if (lane == 0) red[wv] = s;
    __syncthreads();
    if (threadIdx.x == 0) atomicAdd(&acc[2], red[0] + red[1] + red[2] + red[3]);
  }
  if (threadIdx.x == 0) {
    __threadfence();
    float tk = atomicAdd(&acc[3], 1.f);
    if (tk == 2591.f) {
      float c0 = atomicAdd(&acc[0], 0.f);
      float c1 = atomicAdd(&acc[1], 0.f);
      float c2 = atomicAdd(&acc[2], 0.f);
      out_scalars[0] = c0 / fmaxf(c1, 1.f);
      out_scalars[1] = c2 / (float)B_;
    }
  }
}

extern "C" void kernel_launch(void* const* d_in, const int* in_sizes, int n_in,
                              void* d_out, int out_size, void* d_ws, size_t ws_size,
                              hipStream_t stream) {
  const float* base_feat = (const float*)d_in[0];
  const float* W_conv    = (const float*)d_in[1];
  const float* b_conv    = (const float*)d_in[2];
  const float* W_cls     = (const float*)d_in[3];
  const float* b_cls     = (const float*)d_in[4];
  const float* W_bbox    = (const float*)d_in[5];
  const float* b_bbox    = (const float*)d_in[6];
  const int*   rpn_label = (const int*)d_in[7];
  const float* bb_tgt    = (const float*)d_in[8];
  const float* bb_iw     = (const float*)d_in[9];
  const float* bb_ow     = (const float*)d_in[10];

  float* out = (float*)d_out;
  float* out_cls_prob = out;                         // 442368
  float* out_bbox     = out + 442368;                // 884736
  float* out_scalars  = out + 442368 + 884736;       // 2

  // workspace layout
  size_t off = 0;
  auto alloc = [&](size_t bytes) {
    void* p = (char*)d_ws + off;
    off = (off + bytes + 255) & ~(size_t)255;
    return p;
  };
  const size_t XT_BYTES = (size_t)B_ * HP * WP * CIN;              // 27,033,600 (fp8)
  unsigned char*  xt    = (unsigned char*)alloc(XT_BYTES);
  unsigned char*  Wa    = (unsigned char*)alloc((size_t)OC * K9);
  unsigned short* Wh    = (unsigned short*)alloc((size_t)64 * 512 * 2);
  float* head_acc       = (float*)alloc((size_t)64 * NPOS * 4);    // 6.29 MB
  float* accbuf         = (float*)alloc(16);

  prep_fused<<<5552, 256, 0, stream>>>(base_feat, W_conv, W_cls, W_bbox, xt, Wa, Wh,
                                       accbuf, head_acc);
  conv_gemm<<<dim3(192, 4), 256, 0, stream>>>(Wa, xt, b_conv, Wh, head_acc);
  loss_fused<<<2592, 256, 0, stream>>>(head_acc, rpn_label, b_cls, b_bbox,
                                       out_cls_prob, out_bbox, bb_tgt, bb_iw, bb_ow,
                                       accbuf, out_scalars);
}